// Round 15
// baseline (210.184 us; speedup 1.0000x reference)
//
#include <hip/hip_runtime.h>

#define NN 1024
#define NP (NN * NN)
#define NBLK 1024
#define NGRP (NBLK * 16)   // k1: 16384 groups, 2 pairs/group/iter -> 32 iters
#define NTRI 528           // 32*33/2 triangular tile-pair blocks

typedef float f32x4 __attribute__((ext_vector_type(4)));

__device__ __forceinline__ f32x4 ntld(const float* p) {
  return __builtin_nontemporal_load((const f32x4*)p);
}

__device__ __forceinline__ ushort bfr(float f) {
  uint u = __float_as_uint(f);
  return (ushort)((u + 0x7fffu + ((u >> 16) & 1u)) >> 16);
}
__device__ __forceinline__ float ubf(uint u) {
  return __uint_as_float(u << 16);
}

#define DPP_ADD_STAGE(v, ctrl)                                               \
  {                                                                          \
    const int _t = __builtin_amdgcn_update_dpp(                              \
        0, __float_as_int(v), (ctrl), 0xf, 0xf, true);                       \
    (v) += __int_as_float(_t);                                               \
  }

// ---------------- k1: LayerNorm + GEMV (r13-proven), zeroes rowsum+done -----
__global__ __launch_bounds__(256) void k_ln_gemv(
    const float* __restrict__ pairp, const float* __restrict__ gamma,
    const float* __restrict__ beta, const float* __restrict__ W,
    const float* __restrict__ bvec, ushort* __restrict__ xout,
    float* __restrict__ rowsum, int* __restrict__ done)
{
  if (blockIdx.x == 0) {
    for (int k = threadIdx.x; k < NN * 6; k += 256) rowsum[k] = 0.f;
    if (threadIdx.x == 0) *done = 0;
  }

  const int l = threadIdx.x & 15;
  const int group = blockIdx.x * 16 + (threadIdx.x >> 4);

  float ug[8][6], apart[6] = {0, 0, 0, 0, 0, 0}, bpart[6] = {0, 0, 0, 0, 0, 0};
#pragma unroll
  for (int k = 0; k < 2; ++k)
#pragma unroll
    for (int m = 0; m < 4; ++m) {
      const int c = 4 * l + 64 * k + m;
      const int idx = 4 * k + m;
      const float ga = gamma[c], be = beta[c];
#pragma unroll
      for (int d = 0; d < 6; ++d) {
        const float w = W[c * 6 + d];
        ug[idx][d] = ga * w;
        apart[d] += ga * w;
        bpart[d] += be * w;
      }
    }
#pragma unroll
  for (int d = 0; d < 6; ++d)
#pragma unroll
    for (int m = 1; m <= 8; m <<= 1) {
      apart[d] += __shfl_xor(apart[d], m);
      bpart[d] += __shfl_xor(bpart[d], m);
    }
  const float vA = (l == 0) ? apart[0] : (l == 1) ? apart[1] : (l == 2) ? apart[2]
                  : (l == 3) ? apart[3] : (l == 4) ? apart[4] : apart[5];
  float vB = (l == 0) ? bpart[0] : (l == 1) ? bpart[1] : (l == 2) ? bpart[2]
            : (l == 3) ? bpart[3] : (l == 4) ? bpart[4] : bpart[5];
  if (l < 6) vB += bvec[l];

  size_t p = 2 * (size_t)group;
  const float* bp = pairp + p * 128 + 4 * l;
  f32x4 a0 = ntld(bp), b0 = ntld(bp + 64);
  f32x4 a1 = ntld(bp + 128), b1 = ntld(bp + 192);

  for (int it = 0; it < 32; ++it) {
    const size_t pn = p + 2 * NGRP;
    f32x4 na0, nb0, na1, nb1;
    if (it != 31) {
      const float* nbp = pairp + pn * 128 + 4 * l;
      na0 = ntld(nbp); nb0 = ntld(nbp + 64);
      na1 = ntld(nbp + 128); nb1 = ntld(nbp + 192);
    }

    const float xv0[8] = {a0.x, a0.y, a0.z, a0.w, b0.x, b0.y, b0.z, b0.w};
    const float xv1[8] = {a1.x, a1.y, a1.z, a1.w, b1.x, b1.y, b1.z, b1.w};
    float r[16];
#pragma unroll
    for (int k = 0; k < 16; ++k) r[k] = 0.f;
#pragma unroll
    for (int k = 0; k < 8; ++k) {
      r[0] += xv0[k];
      r[1] = fmaf(xv0[k], xv0[k], r[1]);
      r[8] += xv1[k];
      r[9] = fmaf(xv1[k], xv1[k], r[9]);
#pragma unroll
      for (int d = 0; d < 6; ++d) {
        r[2 + d] = fmaf(xv0[k], ug[k][d], r[2 + d]);
        r[10 + d] = fmaf(xv1[k], ug[k][d], r[10 + d]);
      }
    }
#pragma unroll
    for (int k = 0; k < 16; ++k) DPP_ADD_STAGE(r[k], 0xB1);
#pragma unroll
    for (int k = 0; k < 16; ++k) DPP_ADD_STAGE(r[k], 0x4E);
#pragma unroll
    for (int k = 0; k < 16; ++k) DPP_ADD_STAGE(r[k], 0x141);
#pragma unroll
    for (int k = 0; k < 16; ++k) DPP_ADD_STAGE(r[k], 0x140);

    if (l < 6) {
      const float mu0 = r[0] * (1.f / 128.f);
      const float var0 = r[1] * (1.f / 128.f) - mu0 * mu0;
      const float rstd0 = rsqrtf(var0 + 1e-5f);
      const float vg0 = (l == 0) ? r[2] : (l == 1) ? r[3] : (l == 2) ? r[4]
                       : (l == 3) ? r[5] : (l == 4) ? r[6] : r[7];
      xout[p * 6 + l] = bfr(fmaf(rstd0, vg0 - mu0 * vA, vB));

      const float mu1 = r[8] * (1.f / 128.f);
      const float var1 = r[9] * (1.f / 128.f) - mu1 * mu1;
      const float rstd1 = rsqrtf(var1 + 1e-5f);
      const float vg1 = (l == 0) ? r[10] : (l == 1) ? r[11] : (l == 2) ? r[12]
                       : (l == 3) ? r[13] : (l == 4) ? r[14] : r[15];
      xout[(p + 1) * 6 + l] = bfr(fmaf(rstd1, vg1 - mu1 * vA, vB));
    }
    p = pn;
    a0 = na0; b0 = nb0; a1 = na1; b1 = nb1;
  }
}

// ---- k_fused: triangular sym + rowsum -> spin barrier -> lse -> out --------
// LDS tiles persist across the barrier; t buffer never materialized.
__device__ __forceinline__ void phaseA(
    const float* __restrict__ Mr, int rowBand, const float* __restrict__ Mc,
    int colBand, const int* __restrict__ seq, float* __restrict__ rowsum,
    int tid)
{
  float es[4][6];
#pragma unroll
  for (int q = 0; q < 4; ++q) {
    const int e = tid + 256 * q;
    const int r = e >> 5, c = e & 31;
    const int dd = seq[rowBand + r] - seq[colBand + c];
    const bool far = (dd > 3) || (dd < -3);
    const float* mr = &Mr[r * 193 + c * 6];
    const float* mc = &Mc[c * 193 + r * 6];
#pragma unroll
    for (int d = 0; d < 6; ++d)
      es[q][d] = far ? __expf(0.5f * (mr[d] + mc[d])) : 0.f;
  }
#pragma unroll
  for (int q = 0; q < 4; ++q)
#pragma unroll
    for (int d = 0; d < 6; ++d)
#pragma unroll
      for (int m = 1; m <= 16; m <<= 1) es[q][d] += __shfl_xor(es[q][d], m);
  if ((tid & 31) == 0) {
    const int w = tid >> 5;
#pragma unroll
    for (int q = 0; q < 4; ++q) {
      const int i = rowBand + w + 8 * q;
#pragma unroll
      for (int d = 0; d < 6; ++d) atomicAdd(&rowsum[i * 6 + d], es[q][d]);
    }
  }
}

__device__ __forceinline__ void phaseB(
    const float* __restrict__ Mr, int rowBand, const float* __restrict__ Mc,
    int colBand, const int* __restrict__ seq, const float* __restrict__ LSr,
    const float* __restrict__ LSc, float* __restrict__ out, int tid)
{
#pragma unroll
  for (int q = 0; q < 4; ++q) {
    const int e = tid + 256 * q;
    const int r = e >> 5, c = e & 31;
    const int i = rowBand + r, j = colBand + c;
    const int dd = seq[i] - seq[j];
    const bool far = (dd > 3) || (dd < -3);
    const float* mr = &Mr[r * 193 + c * 6];
    const float* mc = &Mc[c * 193 + r * 6];
    float xs[6], chs = 0.f;
#pragma unroll
    for (int d = 0; d < 6; ++d) {
      xs[d] = far ? 0.5f * (mr[d] + mc[d]) : -1000000.f;
      chs += __expf(xs[d]);
    }
    const float c2 = 2.f * __logf(1.f + chs);
    float o[6];
#pragma unroll
    for (int d = 0; d < 6; ++d)
      o[d] = 4.f * xs[d] - c2 - LSr[r * 6 + d] - LSc[c * 6 + d];
    float* op = out + ((size_t)i * NN + j) * 6;
    *(float2*)(op) = make_float2(o[0], o[1]);
    *(float2*)(op + 2) = make_float2(o[2], o[3]);
    *(float2*)(op + 4) = make_float2(o[4], o[5]);
  }
}

__global__ __launch_bounds__(256) void k_fused(
    const ushort* __restrict__ x, const int* __restrict__ seq,
    float* __restrict__ rowsum, int* __restrict__ done,
    float* __restrict__ out)
{
  const int b = blockIdx.x;
  int I = (int)((sqrtf(8.f * b + 1.f) - 1.f) * 0.5f);
  while ((I + 1) * (I + 2) / 2 <= b) ++I;
  while (I * (I + 1) / 2 > b) --I;
  const int J = b - I * (I + 1) / 2;  // J <= I
  const int tid = threadIdx.x;

  __shared__ float M1[32 * 193];  // x[I-band][J-band]
  __shared__ float M2[32 * 193];  // x[J-band][I-band]
  __shared__ float LSI[192], LSJ[192];

  for (int k = tid; k < 768; k += 256) {
    const int m = k / 24, f = (k % 24) * 8;
    {
      const uint4 raw = *(const uint4*)(x + ((size_t)(I * 32 + m) * NN + J * 32) * 6 + f);
      float* dst = &M1[m * 193 + f];
      dst[0] = ubf(raw.x & 0xffff); dst[1] = ubf(raw.x >> 16);
      dst[2] = ubf(raw.y & 0xffff); dst[3] = ubf(raw.y >> 16);
      dst[4] = ubf(raw.z & 0xffff); dst[5] = ubf(raw.z >> 16);
      dst[6] = ubf(raw.w & 0xffff); dst[7] = ubf(raw.w >> 16);
    }
    if (I != J) {
      const uint4 raw = *(const uint4*)(x + ((size_t)(J * 32 + m) * NN + I * 32) * 6 + f);
      float* dst = &M2[m * 193 + f];
      dst[0] = ubf(raw.x & 0xffff); dst[1] = ubf(raw.x >> 16);
      dst[2] = ubf(raw.y & 0xffff); dst[3] = ubf(raw.y >> 16);
      dst[4] = ubf(raw.z & 0xffff); dst[5] = ubf(raw.z >> 16);
      dst[6] = ubf(raw.w & 0xffff); dst[7] = ubf(raw.w >> 16);
    }
  }
  __syncthreads();

  // ---- phase A: rowsum contributions ----
  if (I != J) {
    phaseA(M1, I * 32, M2, J * 32, seq, rowsum, tid);
    phaseA(M2, J * 32, M1, I * 32, seq, rowsum, tid);
  } else {
    phaseA(M1, I * 32, M1, J * 32, seq, rowsum, tid);
  }

  // ---- spin barrier: all 528 blocks resident (3/CU LDS-capacity 768) ----
  __threadfence();   // this thread's atomics visible device-wide
  __syncthreads();   // whole block done
  if (tid == 0) {
    __hip_atomic_fetch_add(done, 1, __ATOMIC_RELEASE, __HIP_MEMORY_SCOPE_AGENT);
    while (__hip_atomic_load(done, __ATOMIC_ACQUIRE, __HIP_MEMORY_SCOPE_AGENT)
           < NTRI) {
      __builtin_amdgcn_s_sleep(8);
    }
  }
  __syncthreads();

  // ---- lse slices for I-band and J-band (agent-scope loads skip stale L1) --
  for (int k = tid; k < 384; k += 256) {
    if (k < 192) {
      const float rs = __hip_atomic_load(&rowsum[I * 192 + k], __ATOMIC_RELAXED,
                                         __HIP_MEMORY_SCOPE_AGENT);
      LSI[k] = __logf(1.f + rs);
    } else {
      const float rs = __hip_atomic_load(&rowsum[J * 192 + (k - 192)],
                                         __ATOMIC_RELAXED,
                                         __HIP_MEMORY_SCOPE_AGENT);
      LSJ[k - 192] = __logf(1.f + rs);
    }
  }
  __syncthreads();

  // ---- phase B: out directly from LDS tiles ----
  if (I != J) {
    phaseB(M1, I * 32, M2, J * 32, seq, LSI, LSJ, out, tid);
    phaseB(M2, J * 32, M1, I * 32, seq, LSJ, LSI, out, tid);
  } else {
    phaseB(M1, I * 32, M1, J * 32, seq, LSI, LSI, out, tid);
  }
}

extern "C" void kernel_launch(void* const* d_in, const int* in_sizes, int n_in,
                              void* d_out, int out_size, void* d_ws, size_t ws_size,
                              hipStream_t stream) {
  const float* pairp = (const float*)d_in[0];
  const int* seq = (const int*)d_in[1];
  const float* gamma = (const float*)d_in[2];
  const float* beta = (const float*)d_in[3];
  const float* W = (const float*)d_in[4];
  const float* bvec = (const float*)d_in[5];
  float* out = (float*)d_out;

  ushort* x = (ushort*)d_ws;                     // bf16 x: 12 MB
  float* rowsum = (float*)(x + (size_t)NP * 6);  // 24 KB
  int* done = (int*)(rowsum + NN * 6);           // 4 B

  k_ln_gemv<<<NBLK, 256, 0, stream>>>(pairp, gamma, beta, W, bvec, x, rowsum,
                                      done);
  k_fused<<<NTRI, 256, 0, stream>>>(x, seq, rowsum, done, out);
}

// Round 16
// 135.222 us; speedup vs baseline: 1.5544x; 1.5544x over previous
//
#include <hip/hip_runtime.h>

#define NN 1024
#define NP (NN * NN)
#define NBLK 1024
#define NGRP (NBLK * 16)   // k1: 16384 groups, 2 pairs/group/iter -> 32 iters

typedef float f32x4 __attribute__((ext_vector_type(4)));

__device__ __forceinline__ f32x4 ntld(const float* p) {
  return __builtin_nontemporal_load((const f32x4*)p);
}

// bf16 helpers (round-to-nearest-even pack, shift unpack)
__device__ __forceinline__ ushort bfr(float f) {
  uint u = __float_as_uint(f);
  return (ushort)((u + 0x7fffu + ((u >> 16) & 1u)) >> 16);
}
__device__ __forceinline__ uint bfr2(float lo, float hi) {
  return (uint)bfr(lo) | ((uint)bfr(hi) << 16);
}
__device__ __forceinline__ float ubf(uint u) {
  return __uint_as_float(u << 16);
}

#define DPP_ADD_STAGE(v, ctrl)                                               \
  {                                                                          \
    const int _t = __builtin_amdgcn_update_dpp(                              \
        0, __float_as_int(v), (ctrl), 0xf, 0xf, true);                       \
    (v) += __int_as_float(_t);                                               \
  }

// ---------------- k1: LayerNorm + GEMV (r13-proven) -------------------------
__global__ __launch_bounds__(256) void k_ln_gemv(
    const float* __restrict__ pairp, const float* __restrict__ gamma,
    const float* __restrict__ beta, const float* __restrict__ W,
    const float* __restrict__ bvec, ushort* __restrict__ xout,
    float* __restrict__ rowsum)
{
  if (blockIdx.x == 0) {
    for (int k = threadIdx.x; k < NN * 6; k += 256) rowsum[k] = 0.f;
  }

  const int l = threadIdx.x & 15;
  const int group = blockIdx.x * 16 + (threadIdx.x >> 4);

  float ug[8][6], apart[6] = {0, 0, 0, 0, 0, 0}, bpart[6] = {0, 0, 0, 0, 0, 0};
#pragma unroll
  for (int k = 0; k < 2; ++k)
#pragma unroll
    for (int m = 0; m < 4; ++m) {
      const int c = 4 * l + 64 * k + m;
      const int idx = 4 * k + m;
      const float ga = gamma[c], be = beta[c];
#pragma unroll
      for (int d = 0; d < 6; ++d) {
        const float w = W[c * 6 + d];
        ug[idx][d] = ga * w;
        apart[d] += ga * w;
        bpart[d] += be * w;
      }
    }
#pragma unroll
  for (int d = 0; d < 6; ++d)
#pragma unroll
    for (int m = 1; m <= 8; m <<= 1) {
      apart[d] += __shfl_xor(apart[d], m);
      bpart[d] += __shfl_xor(bpart[d], m);
    }
  const float vA = (l == 0) ? apart[0] : (l == 1) ? apart[1] : (l == 2) ? apart[2]
                  : (l == 3) ? apart[3] : (l == 4) ? apart[4] : apart[5];
  float vB = (l == 0) ? bpart[0] : (l == 1) ? bpart[1] : (l == 2) ? bpart[2]
            : (l == 3) ? bpart[3] : (l == 4) ? bpart[4] : bpart[5];
  if (l < 6) vB += bvec[l];

  size_t p = 2 * (size_t)group;
  const float* bp = pairp + p * 128 + 4 * l;
  f32x4 a0 = ntld(bp), b0 = ntld(bp + 64);
  f32x4 a1 = ntld(bp + 128), b1 = ntld(bp + 192);

  for (int it = 0; it < 32; ++it) {
    const size_t pn = p + 2 * NGRP;
    f32x4 na0, nb0, na1, nb1;
    if (it != 31) {
      const float* nbp = pairp + pn * 128 + 4 * l;
      na0 = ntld(nbp); nb0 = ntld(nbp + 64);
      na1 = ntld(nbp + 128); nb1 = ntld(nbp + 192);
    }

    const float xv0[8] = {a0.x, a0.y, a0.z, a0.w, b0.x, b0.y, b0.z, b0.w};
    const float xv1[8] = {a1.x, a1.y, a1.z, a1.w, b1.x, b1.y, b1.z, b1.w};
    float r[16];
#pragma unroll
    for (int k = 0; k < 16; ++k) r[k] = 0.f;
#pragma unroll
    for (int k = 0; k < 8; ++k) {
      r[0] += xv0[k];
      r[1] = fmaf(xv0[k], xv0[k], r[1]);
      r[8] += xv1[k];
      r[9] = fmaf(xv1[k], xv1[k], r[9]);
#pragma unroll
      for (int d = 0; d < 6; ++d) {
        r[2 + d] = fmaf(xv0[k], ug[k][d], r[2 + d]);
        r[10 + d] = fmaf(xv1[k], ug[k][d], r[10 + d]);
      }
    }
#pragma unroll
    for (int k = 0; k < 16; ++k) DPP_ADD_STAGE(r[k], 0xB1);
#pragma unroll
    for (int k = 0; k < 16; ++k) DPP_ADD_STAGE(r[k], 0x4E);
#pragma unroll
    for (int k = 0; k < 16; ++k) DPP_ADD_STAGE(r[k], 0x141);
#pragma unroll
    for (int k = 0; k < 16; ++k) DPP_ADD_STAGE(r[k], 0x140);

    if (l < 6) {
      const float mu0 = r[0] * (1.f / 128.f);
      const float var0 = r[1] * (1.f / 128.f) - mu0 * mu0;
      const float rstd0 = rsqrtf(var0 + 1e-5f);
      const float vg0 = (l == 0) ? r[2] : (l == 1) ? r[3] : (l == 2) ? r[4]
                       : (l == 3) ? r[5] : (l == 4) ? r[6] : r[7];
      xout[p * 6 + l] = bfr(fmaf(rstd0, vg0 - mu0 * vA, vB));

      const float mu1 = r[8] * (1.f / 128.f);
      const float var1 = r[9] * (1.f / 128.f) - mu1 * mu1;
      const float rstd1 = rsqrtf(var1 + 1e-5f);
      const float vg1 = (l == 0) ? r[10] : (l == 1) ? r[11] : (l == 2) ? r[12]
                       : (l == 3) ? r[13] : (l == 4) ? r[14] : r[15];
      xout[(p + 1) * 6 + l] = bfr(fmaf(rstd1, vg1 - mu1 * vA, vB));
    }
    p = pn;
    a0 = na0; b0 = nb0; a1 = na1; b1 = nb1;
  }
}

// -------- k_sym2: triangular blocks, each x tile staged exactly once --------
__device__ __forceinline__ void do_tile(
    const float* __restrict__ Mr, const float* __restrict__ Mc,
    int rowBand, int colBand, const int* __restrict__ seq,
    ushort* __restrict__ t, float* __restrict__ rowsum, int tid)
{
  float es[4][6];
#pragma unroll
  for (int q = 0; q < 4; ++q) {
    const int e = tid + 256 * q;
    const int r = e >> 5, c = e & 31;
    const int i = rowBand + r, j = colBand + c;
    const int dd = seq[i] - seq[j];
    const bool far = (dd > 3) || (dd < -3);
    const float* mr = &Mr[r * 193 + c * 6];
    const float* mc = &Mc[c * 193 + r * 6];
    float xs[6], chs = 0.f;
#pragma unroll
    for (int d = 0; d < 6; ++d) {
      xs[d] = far ? 0.5f * (mr[d] + mc[d]) : -1000000.f;
      es[q][d] = __expf(xs[d]);
      chs += es[q][d];
    }
    const float c2 = 2.f * __logf(1.f + chs);
    uint* tp = (uint*)(t + ((size_t)i * NN + j) * 6);
    tp[0] = bfr2(4.f * xs[0] - c2, 4.f * xs[1] - c2);
    tp[1] = bfr2(4.f * xs[2] - c2, 4.f * xs[3] - c2);
    tp[2] = bfr2(4.f * xs[4] - c2, 4.f * xs[5] - c2);
  }
#pragma unroll
  for (int q = 0; q < 4; ++q)
#pragma unroll
    for (int d = 0; d < 6; ++d)
#pragma unroll
      for (int m = 1; m <= 16; m <<= 1) es[q][d] += __shfl_xor(es[q][d], m);
  if ((tid & 31) == 0) {
    const int w = tid >> 5;
#pragma unroll
    for (int q = 0; q < 4; ++q) {
      const int i = rowBand + w + 8 * q;
#pragma unroll
      for (int d = 0; d < 6; ++d) atomicAdd(&rowsum[i * 6 + d], es[q][d]);
    }
  }
}

__global__ __launch_bounds__(256) void k_sym2(
    const ushort* __restrict__ x, const int* __restrict__ seq,
    ushort* __restrict__ t, float* __restrict__ rowsum)
{
  const int b = blockIdx.x;
  int I = (int)((sqrtf(8.f * b + 1.f) - 1.f) * 0.5f);
  while ((I + 1) * (I + 2) / 2 <= b) ++I;
  while (I * (I + 1) / 2 > b) --I;
  const int J = b - I * (I + 1) / 2;  // J <= I
  const int tid = threadIdx.x;

  __shared__ float M1[32 * 193];  // x[I-band][J-band]
  __shared__ float M2[32 * 193];  // x[J-band][I-band]

  for (int k = tid; k < 768; k += 256) {
    const int m = k / 24, f = (k % 24) * 8;
    {
      const uint4 raw = *(const uint4*)(x + ((size_t)(I * 32 + m) * NN + J * 32) * 6 + f);
      float* dst = &M1[m * 193 + f];
      dst[0] = ubf(raw.x & 0xffff); dst[1] = ubf(raw.x >> 16);
      dst[2] = ubf(raw.y & 0xffff); dst[3] = ubf(raw.y >> 16);
      dst[4] = ubf(raw.z & 0xffff); dst[5] = ubf(raw.z >> 16);
      dst[6] = ubf(raw.w & 0xffff); dst[7] = ubf(raw.w >> 16);
    }
    if (I != J) {
      const uint4 raw = *(const uint4*)(x + ((size_t)(J * 32 + m) * NN + I * 32) * 6 + f);
      float* dst = &M2[m * 193 + f];
      dst[0] = ubf(raw.x & 0xffff); dst[1] = ubf(raw.x >> 16);
      dst[2] = ubf(raw.y & 0xffff); dst[3] = ubf(raw.y >> 16);
      dst[4] = ubf(raw.z & 0xffff); dst[5] = ubf(raw.z >> 16);
      dst[6] = ubf(raw.w & 0xffff); dst[7] = ubf(raw.w >> 16);
    }
  }
  __syncthreads();

  if (I != J) {
    do_tile(M1, M2, I * 32, J * 32, seq, t, rowsum, tid);
    do_tile(M2, M1, J * 32, I * 32, seq, t, rowsum, tid);
  } else {
    do_tile(M1, M1, I * 32, J * 32, seq, t, rowsum, tid);
  }
}

// -------- k_lse: lse = log1p(rowsum), 6144 values, one tiny dispatch --------
__global__ __launch_bounds__(256) void k_lse(
    const float* __restrict__ rowsum, float* __restrict__ lse)
{
  const int k = blockIdx.x * 256 + threadIdx.x;
  if (k < NN * 6) lse[k] = __logf(1.0f + rowsum[k]);
}

// -------- k_out2: out = t - lse_i - lse_j (pure stream + L2-hot gathers) ----
__global__ __launch_bounds__(256) void k_out2(
    const ushort* __restrict__ t, const float* __restrict__ lse,
    float* __restrict__ out)
{
  const int b = blockIdx.x;
  const int i = b >> 2;
  const int j = ((b & 3) << 8) + threadIdx.x;

  __shared__ float LSI[6];
  if (threadIdx.x < 6) LSI[threadIdx.x] = lse[i * 6 + threadIdx.x];
  __syncthreads();

  const float2 lj01 = *(const float2*)(lse + j * 6);
  const float2 lj23 = *(const float2*)(lse + j * 6 + 2);
  const float2 lj45 = *(const float2*)(lse + j * 6 + 4);

  const size_t p = (size_t)i * NN + j;
  const uint* tp = (const uint*)(t + p * 6);
  const uint w0 = tp[0], w1 = tp[1], w2 = tp[2];
  float o[6];
  o[0] = ubf(w0 & 0xffff) - LSI[0] - lj01.x;
  o[1] = ubf(w0 >> 16)    - LSI[1] - lj01.y;
  o[2] = ubf(w1 & 0xffff) - LSI[2] - lj23.x;
  o[3] = ubf(w1 >> 16)    - LSI[3] - lj23.y;
  o[4] = ubf(w2 & 0xffff) - LSI[4] - lj45.x;
  o[5] = ubf(w2 >> 16)    - LSI[5] - lj45.y;

  float* op = out + p * 6;
  *(float2*)(op) = make_float2(o[0], o[1]);
  *(float2*)(op + 2) = make_float2(o[2], o[3]);
  *(float2*)(op + 4) = make_float2(o[4], o[5]);
}

extern "C" void kernel_launch(void* const* d_in, const int* in_sizes, int n_in,
                              void* d_out, int out_size, void* d_ws, size_t ws_size,
                              hipStream_t stream) {
  const float* pairp = (const float*)d_in[0];
  const int* seq = (const int*)d_in[1];
  const float* gamma = (const float*)d_in[2];
  const float* beta = (const float*)d_in[3];
  const float* W = (const float*)d_in[4];
  const float* bvec = (const float*)d_in[5];
  float* out = (float*)d_out;

  ushort* x = (ushort*)d_ws;                     // bf16 x: 12 MB
  ushort* t = x + (size_t)NP * 6;                // bf16 t: 12 MB
  float* rowsum = (float*)(t + (size_t)NP * 6);  // 24 KB
  float* lse = rowsum + NN * 6;                  // 24 KB

  k_ln_gemv<<<NBLK, 256, 0, stream>>>(pairp, gamma, beta, W, bvec, x, rowsum);
  k_sym2<<<528, 256, 0, stream>>>(x, seq, t, rowsum);
  k_lse<<<(NN * 6 + 255) / 256, 256, 0, stream>>>(rowsum, lse);
  k_out2<<<NP / 256, 256, 0, stream>>>(t, lse, out);
}

// Round 17
// 133.944 us; speedup vs baseline: 1.5692x; 1.0095x over previous
//
#include <hip/hip_runtime.h>

#define NN 1024
#define NP (NN * NN)
#define NBLK 1024
#define NGRP (NBLK * 16)   // k1: 16384 groups, 2 pairs/group/iter -> 32 iters

typedef float f32x4 __attribute__((ext_vector_type(4)));

__device__ __forceinline__ f32x4 ntld(const float* p) {
  return __builtin_nontemporal_load((const f32x4*)p);
}

// bf16 helpers (round-to-nearest-even pack, shift unpack)
__device__ __forceinline__ ushort bfr(float f) {
  uint u = __float_as_uint(f);
  return (ushort)((u + 0x7fffu + ((u >> 16) & 1u)) >> 16);
}
__device__ __forceinline__ uint bfr2(float lo, float hi) {
  return (uint)bfr(lo) | ((uint)bfr(hi) << 16);
}
__device__ __forceinline__ float ubf(uint u) {
  return __uint_as_float(u << 16);
}

#define DPP_ADD_STAGE(v, ctrl)                                               \
  {                                                                          \
    const int _t = __builtin_amdgcn_update_dpp(                              \
        0, __float_as_int(v), (ctrl), 0xf, 0xf, true);                       \
    (v) += __int_as_float(_t);                                               \
  }

// ---------------- k1: LayerNorm + GEMV (r13-proven) -------------------------
__global__ __launch_bounds__(256) void k_ln_gemv(
    const float* __restrict__ pairp, const float* __restrict__ gamma,
    const float* __restrict__ beta, const float* __restrict__ W,
    const float* __restrict__ bvec, ushort* __restrict__ xout,
    float* __restrict__ rowsum)
{
  if (blockIdx.x == 0) {
    for (int k = threadIdx.x; k < NN * 6; k += 256) rowsum[k] = 0.f;
  }

  const int l = threadIdx.x & 15;
  const int group = blockIdx.x * 16 + (threadIdx.x >> 4);

  float ug[8][6], apart[6] = {0, 0, 0, 0, 0, 0}, bpart[6] = {0, 0, 0, 0, 0, 0};
#pragma unroll
  for (int k = 0; k < 2; ++k)
#pragma unroll
    for (int m = 0; m < 4; ++m) {
      const int c = 4 * l + 64 * k + m;
      const int idx = 4 * k + m;
      const float ga = gamma[c], be = beta[c];
#pragma unroll
      for (int d = 0; d < 6; ++d) {
        const float w = W[c * 6 + d];
        ug[idx][d] = ga * w;
        apart[d] += ga * w;
        bpart[d] += be * w;
      }
    }
#pragma unroll
  for (int d = 0; d < 6; ++d)
#pragma unroll
    for (int m = 1; m <= 8; m <<= 1) {
      apart[d] += __shfl_xor(apart[d], m);
      bpart[d] += __shfl_xor(bpart[d], m);
    }
  const float vA = (l == 0) ? apart[0] : (l == 1) ? apart[1] : (l == 2) ? apart[2]
                  : (l == 3) ? apart[3] : (l == 4) ? apart[4] : apart[5];
  float vB = (l == 0) ? bpart[0] : (l == 1) ? bpart[1] : (l == 2) ? bpart[2]
            : (l == 3) ? bpart[3] : (l == 4) ? bpart[4] : bpart[5];
  if (l < 6) vB += bvec[l];

  size_t p = 2 * (size_t)group;
  const float* bp = pairp + p * 128 + 4 * l;
  f32x4 a0 = ntld(bp), b0 = ntld(bp + 64);
  f32x4 a1 = ntld(bp + 128), b1 = ntld(bp + 192);

  for (int it = 0; it < 32; ++it) {
    const size_t pn = p + 2 * NGRP;
    f32x4 na0, nb0, na1, nb1;
    if (it != 31) {
      const float* nbp = pairp + pn * 128 + 4 * l;
      na0 = ntld(nbp); nb0 = ntld(nbp + 64);
      na1 = ntld(nbp + 128); nb1 = ntld(nbp + 192);
    }

    const float xv0[8] = {a0.x, a0.y, a0.z, a0.w, b0.x, b0.y, b0.z, b0.w};
    const float xv1[8] = {a1.x, a1.y, a1.z, a1.w, b1.x, b1.y, b1.z, b1.w};
    float r[16];
#pragma unroll
    for (int k = 0; k < 16; ++k) r[k] = 0.f;
#pragma unroll
    for (int k = 0; k < 8; ++k) {
      r[0] += xv0[k];
      r[1] = fmaf(xv0[k], xv0[k], r[1]);
      r[8] += xv1[k];
      r[9] = fmaf(xv1[k], xv1[k], r[9]);
#pragma unroll
      for (int d = 0; d < 6; ++d) {
        r[2 + d] = fmaf(xv0[k], ug[k][d], r[2 + d]);
        r[10 + d] = fmaf(xv1[k], ug[k][d], r[10 + d]);
      }
    }
#pragma unroll
    for (int k = 0; k < 16; ++k) DPP_ADD_STAGE(r[k], 0xB1);
#pragma unroll
    for (int k = 0; k < 16; ++k) DPP_ADD_STAGE(r[k], 0x4E);
#pragma unroll
    for (int k = 0; k < 16; ++k) DPP_ADD_STAGE(r[k], 0x141);
#pragma unroll
    for (int k = 0; k < 16; ++k) DPP_ADD_STAGE(r[k], 0x140);

    if (l < 6) {
      const float mu0 = r[0] * (1.f / 128.f);
      const float var0 = r[1] * (1.f / 128.f) - mu0 * mu0;
      const float rstd0 = rsqrtf(var0 + 1e-5f);
      const float vg0 = (l == 0) ? r[2] : (l == 1) ? r[3] : (l == 2) ? r[4]
                       : (l == 3) ? r[5] : (l == 4) ? r[6] : r[7];
      xout[p * 6 + l] = bfr(fmaf(rstd0, vg0 - mu0 * vA, vB));

      const float mu1 = r[8] * (1.f / 128.f);
      const float var1 = r[9] * (1.f / 128.f) - mu1 * mu1;
      const float rstd1 = rsqrtf(var1 + 1e-5f);
      const float vg1 = (l == 0) ? r[10] : (l == 1) ? r[11] : (l == 2) ? r[12]
                       : (l == 3) ? r[13] : (l == 4) ? r[14] : r[15];
      xout[(p + 1) * 6 + l] = bfr(fmaf(rstd1, vg1 - mu1 * vA, vB));
    }
    p = pn;
    a0 = na0; b0 = nb0; a1 = na1; b1 = nb1;
  }
}

// -------- k_sym2: triangular blocks, each x tile staged exactly once --------
__device__ __forceinline__ void do_tile(
    const float* __restrict__ Mr, const float* __restrict__ Mc,
    int rowBand, int colBand, const int* __restrict__ seq,
    ushort* __restrict__ t, float* __restrict__ rowsum, int tid)
{
  float es[4][6];
#pragma unroll
  for (int q = 0; q < 4; ++q) {
    const int e = tid + 256 * q;
    const int r = e >> 5, c = e & 31;
    const int i = rowBand + r, j = colBand + c;
    const int dd = seq[i] - seq[j];
    const bool far = (dd > 3) || (dd < -3);
    const float* mr = &Mr[r * 193 + c * 6];
    const float* mc = &Mc[c * 193 + r * 6];
    float xs[6], chs = 0.f;
#pragma unroll
    for (int d = 0; d < 6; ++d) {
      xs[d] = far ? 0.5f * (mr[d] + mc[d]) : -1000000.f;
      es[q][d] = __expf(xs[d]);
      chs += es[q][d];
    }
    const float c2 = 2.f * __logf(1.f + chs);
    uint* tp = (uint*)(t + ((size_t)i * NN + j) * 6);
    tp[0] = bfr2(4.f * xs[0] - c2, 4.f * xs[1] - c2);
    tp[1] = bfr2(4.f * xs[2] - c2, 4.f * xs[3] - c2);
    tp[2] = bfr2(4.f * xs[4] - c2, 4.f * xs[5] - c2);
  }
#pragma unroll
  for (int q = 0; q < 4; ++q)
#pragma unroll
    for (int d = 0; d < 6; ++d)
#pragma unroll
      for (int m = 1; m <= 16; m <<= 1) es[q][d] += __shfl_xor(es[q][d], m);
  if ((tid & 31) == 0) {
    const int w = tid >> 5;
#pragma unroll
    for (int q = 0; q < 4; ++q) {
      const int i = rowBand + w + 8 * q;
#pragma unroll
      for (int d = 0; d < 6; ++d) atomicAdd(&rowsum[i * 6 + d], es[q][d]);
    }
  }
}

__global__ __launch_bounds__(256) void k_sym2(
    const ushort* __restrict__ x, const int* __restrict__ seq,
    ushort* __restrict__ t, float* __restrict__ rowsum)
{
  const int b = blockIdx.x;
  int I = (int)((sqrtf(8.f * b + 1.f) - 1.f) * 0.5f);
  while ((I + 1) * (I + 2) / 2 <= b) ++I;
  while (I * (I + 1) / 2 > b) --I;
  const int J = b - I * (I + 1) / 2;  // J <= I
  const int tid = threadIdx.x;

  __shared__ float M1[32 * 193];  // x[I-band][J-band]
  __shared__ float M2[32 * 193];  // x[J-band][I-band]

  for (int k = tid; k < 768; k += 256) {
    const int m = k / 24, f = (k % 24) * 8;
    {
      const uint4 raw = *(const uint4*)(x + ((size_t)(I * 32 + m) * NN + J * 32) * 6 + f);
      float* dst = &M1[m * 193 + f];
      dst[0] = ubf(raw.x & 0xffff); dst[1] = ubf(raw.x >> 16);
      dst[2] = ubf(raw.y & 0xffff); dst[3] = ubf(raw.y >> 16);
      dst[4] = ubf(raw.z & 0xffff); dst[5] = ubf(raw.z >> 16);
      dst[6] = ubf(raw.w & 0xffff); dst[7] = ubf(raw.w >> 16);
    }
    if (I != J) {
      const uint4 raw = *(const uint4*)(x + ((size_t)(J * 32 + m) * NN + I * 32) * 6 + f);
      float* dst = &M2[m * 193 + f];
      dst[0] = ubf(raw.x & 0xffff); dst[1] = ubf(raw.x >> 16);
      dst[2] = ubf(raw.y & 0xffff); dst[3] = ubf(raw.y >> 16);
      dst[4] = ubf(raw.z & 0xffff); dst[5] = ubf(raw.z >> 16);
      dst[6] = ubf(raw.w & 0xffff); dst[7] = ubf(raw.w >> 16);
    }
  }
  __syncthreads();

  if (I != J) {
    do_tile(M1, M2, I * 32, J * 32, seq, t, rowsum, tid);
    do_tile(M2, M1, J * 32, I * 32, seq, t, rowsum, tid);
  } else {
    do_tile(M1, M1, I * 32, J * 32, seq, t, rowsum, tid);
  }
}

// -------- k_out2: out = t - lse_i - lse_j (lse = log1p(rowsum), on the fly) --
__global__ __launch_bounds__(256) void k_out2(
    const ushort* __restrict__ t, const float* __restrict__ rowsum,
    float* __restrict__ out)
{
  const int b = blockIdx.x;
  const int i = b >> 2;
  const int j = ((b & 3) << 8) + threadIdx.x;

  __shared__ float LSI[6];
  if (threadIdx.x < 6) LSI[threadIdx.x] = __logf(1.f + rowsum[i * 6 + threadIdx.x]);
  __syncthreads();

  float lj[6];
#pragma unroll
  for (int d = 0; d < 6; ++d) lj[d] = __logf(1.f + rowsum[j * 6 + d]);

  const size_t p = (size_t)i * NN + j;
  const uint* tp = (const uint*)(t + p * 6);
  const uint w0 = tp[0], w1 = tp[1], w2 = tp[2];
  float o[6];
  o[0] = ubf(w0 & 0xffff) - LSI[0] - lj[0];
  o[1] = ubf(w0 >> 16)    - LSI[1] - lj[1];
  o[2] = ubf(w1 & 0xffff) - LSI[2] - lj[2];
  o[3] = ubf(w1 >> 16)    - LSI[3] - lj[3];
  o[4] = ubf(w2 & 0xffff) - LSI[4] - lj[4];
  o[5] = ubf(w2 >> 16)    - LSI[5] - lj[5];

  float* op = out + p * 6;
  *(float2*)(op) = make_float2(o[0], o[1]);
  *(float2*)(op + 2) = make_float2(o[2], o[3]);
  *(float2*)(op + 4) = make_float2(o[4], o[5]);
}

extern "C" void kernel_launch(void* const* d_in, const int* in_sizes, int n_in,
                              void* d_out, int out_size, void* d_ws, size_t ws_size,
                              hipStream_t stream) {
  const float* pairp = (const float*)d_in[0];
  const int* seq = (const int*)d_in[1];
  const float* gamma = (const float*)d_in[2];
  const float* beta = (const float*)d_in[3];
  const float* W = (const float*)d_in[4];
  const float* bvec = (const float*)d_in[5];
  float* out = (float*)d_out;

  ushort* x = (ushort*)d_ws;                     // bf16 x: 12 MB
  ushort* t = x + (size_t)NP * 6;                // bf16 t: 12 MB
  float* rowsum = (float*)(t + (size_t)NP * 6);  // 24 KB

  k_ln_gemv<<<NBLK, 256, 0, stream>>>(pairp, gamma, beta, W, bvec, x, rowsum);
  k_sym2<<<528, 256, 0, stream>>>(x, seq, t, rowsum);
  k_out2<<<NP / 256, 256, 0, stream>>>(t, rowsum, out);
}